// Round 1
// baseline (502.467 us; speedup 1.0000x reference)
//
#include <hip/hip_runtime.h>
#include <hip/hip_bf16.h>

typedef unsigned short u16;
typedef __attribute__((ext_vector_type(8))) short short8;
typedef __attribute__((ext_vector_type(4))) short short4v;
typedef __attribute__((ext_vector_type(4))) float floatx4;

constexpr int SEQ = 4096;
constexpr int DM  = 2048;
constexpr int NH  = 16;
constexpr int HD  = 128;

__device__ inline u16 f2b(float f) {
    __hip_bfloat16 h = __float2bfloat16(f);
    return *reinterpret_cast<u16*>(&h);
}
__device__ inline float b2f(u16 u) {
    __hip_bfloat16 h = *reinterpret_cast<__hip_bfloat16*>(&u);
    return __bfloat162float(h);
}

__device__ __forceinline__ void async_copy16(const u16* g, u16* lds_base) {
    __builtin_amdgcn_global_load_lds(
        (const __attribute__((address_space(1))) unsigned int*)g,
        (__attribute__((address_space(3))) unsigned int*)lds_base,
        16, 0, 0);
}

// ---------------------------------------------------------------------------
__global__ void detect_dtype(const u16* __restrict__ X, int* __restrict__ flag) {
    __shared__ int cnt;
    if (threadIdx.x == 0) cnt = 0;
    __syncthreads();
    int local = 0;
    for (int i = threadIdx.x; i < 4096; i += 256) {
        int e = (X[i] >> 7) & 0xFF;
        if (e >= 0x3C && e <= 0x8D) local++;
    }
    atomicAdd(&cnt, local);
    __syncthreads();
    if (threadIdx.x == 0) *flag = (cnt >= 3890) ? 1 : 0;
}

// One launch converts all 9 float tensors (bf16 passthrough or fp32 round).
struct ConvArgs {
    const void* src[9];
    unsigned long long dstoff[9];  // u16-element offset from base
    int n[9];
};
__global__ void convert_all(ConvArgs a, u16* __restrict__ base,
                            const int* __restrict__ flag) {
    const int t = blockIdx.y;
    const int n = a.n[t];
    const int i = (blockIdx.x * blockDim.x + threadIdx.x) * 8;
    if (i >= n) return;
    u16* out = base + a.dstoff[t];
    if (*flag) {
        *(short8*)&out[i] = *(const short8*)&((const u16*)a.src[t])[i];
    } else {
        const float* p = (const float*)a.src[t];
        u16 tmp[8];
#pragma unroll
        for (int j = 0; j < 8; j++) tmp[j] = f2b(p[i + j]);
        *(short8*)&out[i] = *(const short8*)tmp;
    }
}

// ---------------------------------------------------------------------------
// 256x256 8-phase GEMM core (HK-style schedule in plain HIP).
//   BM=BN=256, BK=64, 512 threads = 8 waves (2M x 4N), per-wave 128x64 out.
//   LDS: 2 dbuf x (A 32KB + B 32KB) = 128 KiB.
//   T2: XOR-swizzle (granule ^= row&7) — linear global_load_lds dest,
//       inverse-swizzled global SOURCE, swizzled ds_read (both-sides rule).
//   T3/T4: 4 phases per K-tile; 1 half-tile (2 x global_load_lds) staged per
//       phase for tile t+1 into the other buffer; single counted
//       s_waitcnt vmcnt(2) per K-tile (never drain 0 in main loop).
//   T5: s_setprio(1) around each 16-MFMA cluster.
// Race-freedom: stages into buf[c^1] issue only after the barrier that
// follows the last ds_reads of buf[c^1] (reads complete before each wave's
// lgkmcnt(0)+MFMA, which precede that barrier).
// ---------------------------------------------------------------------------
__device__ __forceinline__ void gemm256_core(
    const u16* __restrict__ A, const u16* __restrict__ W,
    int m0, int n0, floatx4 (&acc)[8][4])
{
    __shared__ __align__(16) u16 As[2][16384];
    __shared__ __align__(16) u16 Bs[2][16384];
    constexpr int K  = DM;
    constexpr int NT = K / 64;

    const int tid  = threadIdx.x;
    const int lane = tid & 63;
    const int w    = tid >> 6;            // 0..7
    const int qm   = lane & 15;
    const int quad = lane >> 4;
    const int wm   = (w >> 2) * 128;      // wave row offset: 0 / 128
    const int wn   = (w & 3) * 64;        // wave col offset: 0/64/128/192

    // staging map: thread t covers LDS linear bytes [slot*8192 + t*16, +16)
    //   -> tile row = slot*64 + (t>>3), LDS granule = t&7.
    // source pre-swizzle: global granule = (t&7) ^ (row&7).
    const int srow = tid >> 3;                       // 0..63
    const int scol = ((tid & 7) ^ (srow & 7)) * 8;   // elems

    // frag-read swizzle: logical granule (kh*4+quad) ^ (row&7); row&7 == qm&7
    const int fo0 = (quad ^ (qm & 7)) * 8;   // kh=0 elem offset within row
    const int fo1 = fo0 ^ 32;                // kh=1 (granule ^4 -> elems ^32)

    const u16* Ag = A + (size_t)(m0 + srow) * K + scol;
    const u16* Wg = W + (size_t)(n0 + srow) * K + scol;

#define STG_A(s, b, k0) async_copy16(Ag + (size_t)(s) * 64 * K + (k0), &As[b][(s) * 4096 + w * 512])
#define STG_B(s, b, k0) async_copy16(Wg + (size_t)(s) * 64 * K + (k0), &Bs[b][(s) * 4096 + w * 512])

#pragma unroll
    for (int i = 0; i < 8; ++i)
#pragma unroll
        for (int j = 0; j < 4; ++j) acc[i][j] = floatx4{0.f, 0.f, 0.f, 0.f};

    // prologue: tile 0 -> buffer 0 (8 loads in flight)
#pragma unroll
    for (int s = 0; s < 4; ++s) STG_A(s, 0, 0);
#pragma unroll
    for (int s = 0; s < 4; ++s) STG_B(s, 0, 0);

    short8 bf[4][2];   // B frags for current K-tile, live across 4 phases

    for (int t = 0; t < NT; ++t) {
        const int cb = t & 1, nb = cb ^ 1;
        const int kn = (t + 1) * 64;
        const u16* Ac = As[cb];
        const u16* Bc = Bs[cb];
        const bool more = (t + 1 < NT);
#pragma unroll
        for (int q = 0; q < 4; ++q) {
            // stage one half-tile of tile t+1 into the other buffer
            if (more) {
                if      (q == 0) { STG_A(0, nb, kn); STG_A(1, nb, kn); }
                else if (q == 1) { STG_A(2, nb, kn); STG_A(3, nb, kn); }
                else if (q == 2) { STG_B(0, nb, kn); STG_B(1, nb, kn); }
                else             { STG_B(2, nb, kn); STG_B(3, nb, kn); }
            }
            short8 a00, a01, a10, a11;
            if (q == 0) {
                // counted wait: tile t's 8 loads done; t+1's first 2 in flight
                if (more) asm volatile("s_waitcnt vmcnt(2)" ::: "memory");
                else      asm volatile("s_waitcnt vmcnt(0)" ::: "memory");
                __builtin_amdgcn_s_barrier();   // tile t resident for ALL waves
#pragma unroll
                for (int nt = 0; nt < 4; ++nt) {
                    const int br = wn + nt * 16 + qm;
                    bf[nt][0] = *(const short8*)&Bc[br * 64 + fo0];
                    bf[nt][1] = *(const short8*)&Bc[br * 64 + fo1];
                }
                const int r0 = wm + qm, r1 = wm + 16 + qm;
                a00 = *(const short8*)&Ac[r0 * 64 + fo0];
                a01 = *(const short8*)&Ac[r0 * 64 + fo1];
                a10 = *(const short8*)&Ac[r1 * 64 + fo0];
                a11 = *(const short8*)&Ac[r1 * 64 + fo1];
            } else {
                const int r0 = wm + (2 * q) * 16 + qm, r1 = r0 + 16;
                a00 = *(const short8*)&Ac[r0 * 64 + fo0];
                a01 = *(const short8*)&Ac[r0 * 64 + fo1];
                a10 = *(const short8*)&Ac[r1 * 64 + fo0];
                a11 = *(const short8*)&Ac[r1 * 64 + fo1];
                __builtin_amdgcn_s_barrier();   // phase alignment
            }
            asm volatile("s_waitcnt lgkmcnt(0)" ::: "memory");
            __builtin_amdgcn_sched_barrier(0);
            __builtin_amdgcn_s_setprio(1);
#pragma unroll
            for (int nt = 0; nt < 4; ++nt) {
                acc[2*q][nt]   = __builtin_amdgcn_mfma_f32_16x16x32_bf16(a00, bf[nt][0], acc[2*q][nt], 0, 0, 0);
                acc[2*q][nt]   = __builtin_amdgcn_mfma_f32_16x16x32_bf16(a01, bf[nt][1], acc[2*q][nt], 0, 0, 0);
                acc[2*q+1][nt] = __builtin_amdgcn_mfma_f32_16x16x32_bf16(a10, bf[nt][0], acc[2*q+1][nt], 0, 0, 0);
                acc[2*q+1][nt] = __builtin_amdgcn_mfma_f32_16x16x32_bf16(a11, bf[nt][1], acc[2*q+1][nt], 0, 0, 0);
            }
            __builtin_amdgcn_s_setprio(0);
            __builtin_amdgcn_s_barrier();
        }
    }
#undef STG_A
#undef STG_B
}

// ---------------------------------------------------------------------------
// Fused QKV GEMM: [Q|K|V](4096x6144) = X @ Wall^T + ball. Q,K row-major;
// V written transposed. 256x256 tiles -> grid (24,16).
// ---------------------------------------------------------------------------
__launch_bounds__(512, 2)
__global__ void gemm_qkv(const u16* __restrict__ A, const u16* __restrict__ W,
                         const u16* __restrict__ bias,
                         u16* __restrict__ Qb, u16* __restrict__ Kb,
                         u16* __restrict__ VtG) {
    const int m0 = blockIdx.y * 256;
    const int n0 = blockIdx.x * 256;
    floatx4 acc[8][4];
    gemm256_core(A, W, m0, n0, acc);

    const int tid  = threadIdx.x;
    const int lane = tid & 63;
    const int w    = tid >> 6;
    const int qm   = lane & 15;
    const int quad = lane >> 4;
    const int wm   = (w >> 2) * 128;
    const int wn   = (w & 3) * 64;

    const int buf = n0 >> 11;  // 0=Q, 1=K, 2=V (block-uniform: 2048%256==0)
    if (buf < 2) {
        u16* Y = (buf == 0) ? Qb : Kb;
#pragma unroll
        for (int nt = 0; nt < 4; ++nt) {
            const int gcol = n0 + wn + nt * 16 + qm;
            const int col  = gcol & 2047;
            const float bv = b2f(bias[gcol]);
#pragma unroll
            for (int mt = 0; mt < 8; ++mt) {
                const int rbase = m0 + wm + mt * 16 + quad * 4;
#pragma unroll
                for (int r = 0; r < 4; ++r)
                    Y[(size_t)(rbase + r) * DM + col] = f2b(acc[mt][nt][r] + bv);
            }
        }
    } else {
#pragma unroll
        for (int nt = 0; nt < 4; ++nt) {
            const int gcol = n0 + wn + nt * 16 + qm;
            const int col  = gcol & 2047;            // d-index
            const float bv = b2f(bias[gcol]);
#pragma unroll
            for (int mt = 0; mt < 8; ++mt) {
                const int rbase = m0 + wm + mt * 16 + quad * 4;
                u16 tmp[4];
#pragma unroll
                for (int r = 0; r < 4; ++r)
                    tmp[r] = f2b(acc[mt][nt][r] + bv);
                *(short4v*)&VtG[(size_t)col * SEQ + rbase] = *(const short4v*)tmp;
            }
        }
    }
}

// ---------------------------------------------------------------------------
// Output GEMM: d_out = Ab @ Wo^T + bo, written in the harness's dtype.
// 256x256 tiles -> grid (8,16).
// ---------------------------------------------------------------------------
__launch_bounds__(512, 2)
__global__ void gemm_out(const u16* __restrict__ A, const u16* __restrict__ W,
                         const u16* __restrict__ bias, void* __restrict__ out,
                         const int* __restrict__ flag) {
    const int m0 = blockIdx.y * 256;
    const int n0 = blockIdx.x * 256;
    floatx4 acc[8][4];
    gemm256_core(A, W, m0, n0, acc);

    const int tid  = threadIdx.x;
    const int lane = tid & 63;
    const int w    = tid >> 6;
    const int qm   = lane & 15;
    const int quad = lane >> 4;
    const int wm   = (w >> 2) * 128;
    const int wn   = (w & 3) * 64;
    const int N    = DM;

    const int f = *flag;
#pragma unroll
    for (int nt = 0; nt < 4; ++nt) {
        const int col = n0 + wn + nt * 16 + qm;
        const float bv = b2f(bias[col]);
#pragma unroll
        for (int mt = 0; mt < 8; ++mt) {
            const int rbase = m0 + wm + mt * 16 + quad * 4;
#pragma unroll
            for (int r = 0; r < 4; ++r) {
                const float v = acc[mt][nt][r] + bv;
                if (f) ((u16*)out)[(size_t)(rbase + r) * N + col] = f2b(v);
                else   ((float*)out)[(size_t)(rbase + r) * N + col] = v;
            }
        }
    }
}

// ---------------------------------------------------------------------------
// Flash attention: unchanged this round (512 thr, 8 waves x 16 q-rows,
// causal balance flip, BK=64, fixed-shift softmax, register-prefetch dbuf).
// ---------------------------------------------------------------------------
__launch_bounds__(512)
__global__ void attn_kernel(const u16* __restrict__ Q, const u16* __restrict__ K,
                            const u16* __restrict__ Vt, u16* __restrict__ O,
                            const int* __restrict__ is_causal_p) {
    __shared__ __align__(16) u16 Ks[64][136];
    __shared__ __align__(16) u16 Vts[128][72];
    __shared__ __align__(16) u16 Pb[8][16][72];

    const int tid  = threadIdx.x;
    const int lane = tid & 63;
    const int w    = tid >> 6;                 // 0..7
    const int qm   = lane & 15;
    const int quad = lane >> 4;
    const int xt   = ((blockIdx.y >> 3) & 1) ? (gridDim.x - 1 - blockIdx.x)
                                             : blockIdx.x;
    const int q0   = xt * 128;
    const int h    = blockIdx.y;
    const int causal = *is_causal_p;
    const float scale = 0.08838834764831845f;  // 1/sqrt(128)
    const float SHIFT = 16.0f;                 // exact (softmax shift-invariant)

    short8 qf[4];
    {
        const u16* qptr = Q + (size_t)(q0 + w * 16 + qm) * DM + h * HD;
#pragma unroll
        for (int kc = 0; kc < 4; kc++)
            qf[kc] = *(const short8*)&qptr[kc * 32 + quad * 8];
    }

    floatx4 o[8];
#pragma unroll
    for (int dt = 0; dt < 8; dt++) o[dt] = floatx4{0.f, 0.f, 0.f, 0.f};
    float l_part[4] = {0.f, 0.f, 0.f, 0.f};

    const int jend = causal ? (q0 + 128) : SEQ;

    // staging map (512 thr): chunk c = tid + p*512
    const int kr0 = tid >> 4;            // K row (p adds 32)
    const int kc8 = (tid & 15) * 8;
    const int vd0 = tid >> 3;            // V d   (p adds 64)
    const int vc8 = (tid & 7) * 8;

    short8 kreg[2], vreg[2];
#pragma unroll
    for (int p = 0; p < 2; p++) {
        kreg[p] = *(const short8*)&K[(size_t)(kr0 + p * 32) * DM + h * HD + kc8];
        vreg[p] = *(const short8*)&Vt[(size_t)(h * HD + vd0 + p * 64) * SEQ + vc8];
    }

    for (int j0 = 0; j0 < jend; j0 += 64) {
        // commit prefetched tile to LDS
#pragma unroll
        for (int p = 0; p < 2; p++) {
            *(short8*)&Ks[kr0 + p * 32][kc8] = kreg[p];
            *(short8*)&Vts[vd0 + p * 64][vc8] = vreg[p];
        }
        __syncthreads();

        // prefetch next tile into regs (latency hidden behind compute)
        const int jn = (j0 + 64 < jend) ? j0 + 64 : 0;
#pragma unroll
        for (int p = 0; p < 2; p++) {
            kreg[p] = *(const short8*)&K[(size_t)(jn + kr0 + p * 32) * DM + h * HD + kc8];
            vreg[p] = *(const short8*)&Vt[(size_t)(h * HD + vd0 + p * 64) * SEQ + jn + vc8];
        }

        // S = Q @ K^T
        floatx4 s[4];
#pragma unroll
        for (int nt = 0; nt < 4; nt++) s[nt] = floatx4{0.f, 0.f, 0.f, 0.f};
#pragma unroll
        for (int kc = 0; kc < 4; kc++)
#pragma unroll
            for (int nt = 0; nt < 4; nt++) {
                short8 b = *(const short8*)&Ks[nt * 16 + qm][kc * 32 + quad * 8];
                s[nt] = __builtin_amdgcn_mfma_f32_16x16x32_bf16(qf[kc], b, s[nt], 0, 0, 0);
            }

        // P = exp(S*scale - SHIFT), masked; per-lane partial row sums
        const bool mask = causal && (j0 + 64 > q0 + w * 16);
#pragma unroll
        for (int r = 0; r < 4; r++) {
            const int qg = q0 + w * 16 + quad * 4 + r;
#pragma unroll
            for (int nt = 0; nt < 4; nt++) {
                float v = fmaf(s[nt][r], scale, -SHIFT);
                if (mask && (j0 + nt * 16 + qm > qg)) v = -1e30f;
                const float p = __expf(v);
                l_part[r] += p;
                Pb[w][quad * 4 + r][nt * 16 + qm] = f2b(p);
            }
        }
        asm volatile("s_waitcnt lgkmcnt(0)" ::: "memory");  // Pb is wave-local

        // O += P @ V
#pragma unroll
        for (int kc = 0; kc < 2; kc++) {
            short8 pf = *(const short8*)&Pb[w][qm][kc * 32 + quad * 8];
#pragma unroll
            for (int dt = 0; dt < 8; dt++) {
                short8 b = *(const short8*)&Vts[dt * 16 + qm][kc * 32 + quad * 8];
                o[dt] = __builtin_amdgcn_mfma_f32_16x16x32_bf16(pf, b, o[dt], 0, 0, 0);
            }
        }
        __syncthreads();   // all waves done reading Ks/Vts before next commit
    }

    // Epilogue: quad-local l reduction, normalize, store
#pragma unroll
    for (int r = 0; r < 4; r++) {
        float l = l_part[r];
#pragma unroll
        for (int off = 8; off >= 1; off >>= 1)
            l += __shfl_xor(l, off, 64);
        const float inv = 1.0f / l;
        const int qg = q0 + w * 16 + quad * 4 + r;
#pragma unroll
        for (int dt = 0; dt < 8; dt++) {
            const int d = h * HD + dt * 16 + qm;
            O[(size_t)qg * DM + d] = f2b(o[dt][r] * inv);
        }
    }
}

// ---------------------------------------------------------------------------
extern "C" void kernel_launch(void* const* d_in, const int* in_sizes, int n_in,
                              void* d_out, int out_size, void* d_ws, size_t ws_size,
                              hipStream_t stream) {
    const int* isc = (const int*)d_in[9];

    int* flag = (int*)d_ws;
    u16* base = (u16*)((char*)d_ws + 256);

    const int NX = SEQ * DM;       // 8388608
    const int NW = DM * DM;        // 4194304
    const int NB = DM;

    // ws layout (u16 elems from base):
    unsigned long long off = 0;
    const unsigned long long oXc   = off; off += NX;
    const unsigned long long oWall = off; off += 3ull * NW;  // Wq,Wk,Wv
    const unsigned long long oWo   = off; off += NW;
    const unsigned long long oBall = off; off += 3ull * NB;  // bq,bk,bv
    const unsigned long long oBo   = off; off += NB;
    const unsigned long long oQ    = off; off += NX;
    const unsigned long long oK    = off; off += NX;
    const unsigned long long oVt   = off; off += NX;
    const unsigned long long oA    = off; off += NX;

    detect_dtype<<<1, 256, 0, stream>>>((const u16*)d_in[0], flag);

    ConvArgs ca;
    const unsigned long long dsts[9] = {oXc, oWall, oBall, oWall + NW, oBall + NB,
                                        oWall + 2ull * NW, oBall + 2ull * NB, oWo, oBo};
    for (int i = 0; i < 9; i++) {
        ca.src[i] = d_in[i];
        ca.dstoff[i] = dsts[i];
        ca.n[i] = in_sizes[i];
    }
    convert_all<<<dim3(NX / 8 / 256, 9), 256, 0, stream>>>(ca, base, flag);

    gemm_qkv<<<dim3(3 * DM / 256, SEQ / 256), 512, 0, stream>>>(
        base + oXc, base + oWall, base + oBall,
        base + oQ, base + oK, base + oVt);

    attn_kernel<<<dim3(SEQ / 128, NH), 512, 0, stream>>>(
        base + oQ, base + oK, base + oVt, base + oA, isc);

    gemm_out<<<dim3(DM / 256, SEQ / 256), 512, 0, stream>>>(
        base + oA, base + oWo, base + oBo, d_out, flag);
}

// Round 2
// 479.667 us; speedup vs baseline: 1.0475x; 1.0475x over previous
//
#include <hip/hip_runtime.h>
#include <hip/hip_bf16.h>

typedef unsigned short u16;
typedef __attribute__((ext_vector_type(8))) short short8;
typedef __attribute__((ext_vector_type(4))) short short4v;
typedef __attribute__((ext_vector_type(4))) float floatx4;

constexpr int SEQ = 4096;
constexpr int DM  = 2048;
constexpr int NH  = 16;
constexpr int HD  = 128;

__device__ inline u16 f2b(float f) {
    __hip_bfloat16 h = __float2bfloat16(f);
    return *reinterpret_cast<u16*>(&h);
}
__device__ inline float b2f(u16 u) {
    __hip_bfloat16 h = *reinterpret_cast<__hip_bfloat16*>(&u);
    return __bfloat162float(h);
}

__device__ __forceinline__ void async_copy16(const u16* g, u16* lds_base) {
    __builtin_amdgcn_global_load_lds(
        (const __attribute__((address_space(1))) unsigned int*)g,
        (__attribute__((address_space(3))) unsigned int*)lds_base,
        16, 0, 0);
}

// ---------------------------------------------------------------------------
__global__ void detect_dtype(const u16* __restrict__ X, int* __restrict__ flag) {
    __shared__ int cnt;
    if (threadIdx.x == 0) cnt = 0;
    __syncthreads();
    int local = 0;
    for (int i = threadIdx.x; i < 4096; i += 256) {
        int e = (X[i] >> 7) & 0xFF;
        if (e >= 0x3C && e <= 0x8D) local++;
    }
    atomicAdd(&cnt, local);
    __syncthreads();
    if (threadIdx.x == 0) *flag = (cnt >= 3890) ? 1 : 0;
}

// One launch converts all 9 float tensors (bf16 passthrough or fp32 round).
struct ConvArgs {
    const void* src[9];
    unsigned long long dstoff[9];  // u16-element offset from base
    int n[9];
};
__global__ void convert_all(ConvArgs a, u16* __restrict__ base,
                            const int* __restrict__ flag) {
    const int t = blockIdx.y;
    const int n = a.n[t];
    const int i = (blockIdx.x * blockDim.x + threadIdx.x) * 8;
    if (i >= n) return;
    u16* out = base + a.dstoff[t];
    if (*flag) {
        *(short8*)&out[i] = *(const short8*)&((const u16*)a.src[t])[i];
    } else {
        const float* p = (const float*)a.src[t];
        u16 tmp[8];
#pragma unroll
        for (int j = 0; j < 8; j++) tmp[j] = f2b(p[i + j]);
        *(short8*)&out[i] = *(const short8*)tmp;
    }
}

// ---------------------------------------------------------------------------
// 256x256 GEMM core, 2-sync-per-K-tile schedule.
//   BM=BN=256, BK=64, 512 threads = 8 waves (2M x 4N), per-wave 128x64 out.
//   LDS: 2 parity slots x (A 32KB + B 32KB) = 128 KiB.
//   T2 swizzle: linear global_load_lds dest, inverse-swizzled global SOURCE,
//      swizzled ds_read (granule ^= row&7).
//   Staging at matrix granularity, placed at maximal issue->consume distance:
//      B(t+2) staged at S1 (after MFMA q0: B(t) reads are done) -> ~7 phases
//      A(t+2) staged at S2 (end of tile: A(t) reads are done)   -> 4 phases
//   One counted wait per K-tile: vmcnt(4) at S2 (allows B(t+2)'s 4 loads in
//   flight, forces all of tile t+1 landed; per-wave FIFO makes this exact).
//   Each wave's own vmcnt precedes the barrier => cross-wave residency holds.
//   Only 2 barriers per K-tile; ds_reads for phase k+1 issued before MFMA k.
// ---------------------------------------------------------------------------
__device__ __forceinline__ void gemm256_core(
    const u16* __restrict__ A, const u16* __restrict__ W,
    int m0, int n0, floatx4 (&acc)[8][4])
{
    __shared__ __align__(16) u16 As[2][16384];
    __shared__ __align__(16) u16 Bs[2][16384];
    constexpr int K  = DM;
    constexpr int NT = K / 64;   // 32

    const int tid  = threadIdx.x;
    const int lane = tid & 63;
    const int w    = tid >> 6;            // 0..7
    const int qm   = lane & 15;
    const int quad = lane >> 4;
    const int wm   = (w >> 2) * 128;      // wave row offset: 0 / 128
    const int wn   = (w & 3) * 64;        // wave col offset: 0/64/128/192

    // staging map: thread t covers LDS linear bytes [slot*8192 + t*16, +16)
    // source pre-swizzle: global granule = (t&7) ^ (row&7).
    const int srow = tid >> 3;                       // 0..63
    const int scol = ((tid & 7) ^ (srow & 7)) * 8;   // elems

    // frag-read swizzle: physical granule = (kh*4+quad) ^ (row&7); row&7==qm&7
    const int fo0 = (quad ^ (qm & 7)) * 8;   // kh=0 elem offset within row
    const int fo1 = fo0 ^ 32;                // kh=1

    const u16* Ag = A + (size_t)(m0 + srow) * K + scol;
    const u16* Wg = W + (size_t)(n0 + srow) * K + scol;

#define STG_A4(par, k0) {                                                 \
    async_copy16(Ag + (size_t)0 * 64 * K + (k0), &As[par][0 * 4096 + w * 512]); \
    async_copy16(Ag + (size_t)1 * 64 * K + (k0), &As[par][1 * 4096 + w * 512]); \
    async_copy16(Ag + (size_t)2 * 64 * K + (k0), &As[par][2 * 4096 + w * 512]); \
    async_copy16(Ag + (size_t)3 * 64 * K + (k0), &As[par][3 * 4096 + w * 512]); }
#define STG_B4(par, k0) {                                                 \
    async_copy16(Wg + (size_t)0 * 64 * K + (k0), &Bs[par][0 * 4096 + w * 512]); \
    async_copy16(Wg + (size_t)1 * 64 * K + (k0), &Bs[par][1 * 4096 + w * 512]); \
    async_copy16(Wg + (size_t)2 * 64 * K + (k0), &Bs[par][2 * 4096 + w * 512]); \
    async_copy16(Wg + (size_t)3 * 64 * K + (k0), &Bs[par][3 * 4096 + w * 512]); }

#define RD_A(d0, d1, row) { d0 = *(const short8*)&Ac[(row) * 64 + fo0];   \
                            d1 = *(const short8*)&Ac[(row) * 64 + fo1]; }

#define MFMA_Q(q2, x00, x01, x10, x11) {                                  \
    __builtin_amdgcn_s_setprio(1);                                        \
    _Pragma("unroll")                                                     \
    for (int nt = 0; nt < 4; ++nt) {                                      \
        acc[q2][nt]     = __builtin_amdgcn_mfma_f32_16x16x32_bf16(x00, bf[nt][0], acc[q2][nt], 0, 0, 0);     \
        acc[q2][nt]     = __builtin_amdgcn_mfma_f32_16x16x32_bf16(x01, bf[nt][1], acc[q2][nt], 0, 0, 0);     \
        acc[q2 + 1][nt] = __builtin_amdgcn_mfma_f32_16x16x32_bf16(x10, bf[nt][0], acc[q2 + 1][nt], 0, 0, 0); \
        acc[q2 + 1][nt] = __builtin_amdgcn_mfma_f32_16x16x32_bf16(x11, bf[nt][1], acc[q2 + 1][nt], 0, 0, 0); \
    }                                                                     \
    __builtin_amdgcn_s_setprio(0); }

#pragma unroll
    for (int i = 0; i < 8; ++i)
#pragma unroll
        for (int j = 0; j < 4; ++j) acc[i][j] = floatx4{0.f, 0.f, 0.f, 0.f};

    // Prologue: tiles 0 and 1 (16 loads); wait tile 0 (allow tile 1's 8).
    STG_A4(0, 0);
    STG_B4(0, 0);
    STG_A4(1, 64);
    STG_B4(1, 64);
    asm volatile("s_waitcnt vmcnt(8)" ::: "memory");
    __builtin_amdgcn_s_barrier();
    asm volatile("" ::: "memory");

    for (int t = 0; t < NT; ++t) {
        const int p = t & 1;
        const u16* Ac = As[p];
        const u16* Bc = Bs[p];
        const bool more = (t + 2 < NT);
        const int kf = (t + 2) * 64;

        short8 bf[4][2];
        short8 a0, a1, a2, a3, b0, b1, b2, b3;
        short8 c0, c1, c2, c3, d0, d1, d2, d3;

        // ---- phase 1: B frags + A rows 0,1; prefetch A rows 2,3; MFMA q0
#pragma unroll
        for (int nt = 0; nt < 4; ++nt) {
            const int br = wn + nt * 16 + qm;
            bf[nt][0] = *(const short8*)&Bc[br * 64 + fo0];
            bf[nt][1] = *(const short8*)&Bc[br * 64 + fo1];
        }
        RD_A(a0, a1, wm + qm);
        RD_A(a2, a3, wm + 16 + qm);
        RD_A(b0, b1, wm + 32 + qm);     // prefetch phase 2
        RD_A(b2, b3, wm + 48 + qm);
        MFMA_Q(0, a0, a1, a2, a3);

        // ---- phase 2: prefetch A rows 4,5; MFMA q1
        RD_A(c0, c1, wm + 64 + qm);
        RD_A(c2, c3, wm + 80 + qm);
        MFMA_Q(2, b0, b1, b2, b3);

        // ---- S1: B(t) reads done by all waves -> stage B(t+2) into Bs[p]
        asm volatile("" ::: "memory");
        __builtin_amdgcn_s_barrier();
        asm volatile("" ::: "memory");
        if (more) { STG_B4(p, kf); }

        // ---- phase 3: prefetch A rows 6,7; MFMA q2
        RD_A(d0, d1, wm + 96 + qm);
        RD_A(d2, d3, wm + 112 + qm);
        MFMA_Q(4, c0, c1, c2, c3);

        // ---- phase 4: MFMA q3
        MFMA_Q(6, d0, d1, d2, d3);

        // ---- S2: counted wait (tile t+1 landed; B(t+2)'s 4 may fly);
        //          A(t) reads done -> stage A(t+2) into As[p]
        if (more) asm volatile("s_waitcnt vmcnt(4)" ::: "memory");
        else      asm volatile("s_waitcnt vmcnt(0)" ::: "memory");
        __builtin_amdgcn_s_barrier();
        asm volatile("" ::: "memory");
        if (more) { STG_A4(p, kf); }
    }
#undef STG_A4
#undef STG_B4
#undef RD_A
#undef MFMA_Q
}

// ---------------------------------------------------------------------------
// Fused QKV GEMM: [Q|K|V](4096x6144) = X @ Wall^T + ball. Q,K row-major;
// V written transposed. 256x256 tiles -> grid (24,16).
// ---------------------------------------------------------------------------
__launch_bounds__(512, 2)
__global__ void gemm_qkv(const u16* __restrict__ A, const u16* __restrict__ W,
                         const u16* __restrict__ bias,
                         u16* __restrict__ Qb, u16* __restrict__ Kb,
                         u16* __restrict__ VtG) {
    const int m0 = blockIdx.y * 256;
    const int n0 = blockIdx.x * 256;
    floatx4 acc[8][4];
    gemm256_core(A, W, m0, n0, acc);

    const int tid  = threadIdx.x;
    const int lane = tid & 63;
    const int w    = tid >> 6;
    const int qm   = lane & 15;
    const int quad = lane >> 4;
    const int wm   = (w >> 2) * 128;
    const int wn   = (w & 3) * 64;

    const int buf = n0 >> 11;  // 0=Q, 1=K, 2=V (block-uniform: 2048%256==0)
    if (buf < 2) {
        u16* Y = (buf == 0) ? Qb : Kb;
#pragma unroll
        for (int nt = 0; nt < 4; ++nt) {
            const int gcol = n0 + wn + nt * 16 + qm;
            const int col  = gcol & 2047;
            const float bv = b2f(bias[gcol]);
#pragma unroll
            for (int mt = 0; mt < 8; ++mt) {
                const int rbase = m0 + wm + mt * 16 + quad * 4;
#pragma unroll
                for (int r = 0; r < 4; ++r)
                    Y[(size_t)(rbase + r) * DM + col] = f2b(acc[mt][nt][r] + bv);
            }
        }
    } else {
#pragma unroll
        for (int nt = 0; nt < 4; ++nt) {
            const int gcol = n0 + wn + nt * 16 + qm;
            const int col  = gcol & 2047;            // d-index
            const float bv = b2f(bias[gcol]);
#pragma unroll
            for (int mt = 0; mt < 8; ++mt) {
                const int rbase = m0 + wm + mt * 16 + quad * 4;
                u16 tmp[4];
#pragma unroll
                for (int r = 0; r < 4; ++r)
                    tmp[r] = f2b(acc[mt][nt][r] + bv);
                *(short4v*)&VtG[(size_t)col * SEQ + rbase] = *(const short4v*)tmp;
            }
        }
    }
}

// ---------------------------------------------------------------------------
// Output GEMM: d_out = Ab @ Wo^T + bo, written in the harness's dtype.
// 256x256 tiles -> grid (8,16).
// ---------------------------------------------------------------------------
__launch_bounds__(512, 2)
__global__ void gemm_out(const u16* __restrict__ A, const u16* __restrict__ W,
                         const u16* __restrict__ bias, void* __restrict__ out,
                         const int* __restrict__ flag) {
    const int m0 = blockIdx.y * 256;
    const int n0 = blockIdx.x * 256;
    floatx4 acc[8][4];
    gemm256_core(A, W, m0, n0, acc);

    const int tid  = threadIdx.x;
    const int lane = tid & 63;
    const int w    = tid >> 6;
    const int qm   = lane & 15;
    const int quad = lane >> 4;
    const int wm   = (w >> 2) * 128;
    const int wn   = (w & 3) * 64;
    const int N    = DM;

    const int f = *flag;
#pragma unroll
    for (int nt = 0; nt < 4; ++nt) {
        const int col = n0 + wn + nt * 16 + qm;
        const float bv = b2f(bias[col]);
#pragma unroll
        for (int mt = 0; mt < 8; ++mt) {
            const int rbase = m0 + wm + mt * 16 + quad * 4;
#pragma unroll
            for (int r = 0; r < 4; ++r) {
                const float v = acc[mt][nt][r] + bv;
                if (f) ((u16*)out)[(size_t)(rbase + r) * N + col] = f2b(v);
                else   ((float*)out)[(size_t)(rbase + r) * N + col] = v;
            }
        }
    }
}

// ---------------------------------------------------------------------------
// Flash attention: unchanged this round (512 thr, 8 waves x 16 q-rows,
// causal balance flip, BK=64, fixed-shift softmax, register-prefetch dbuf).
// ---------------------------------------------------------------------------
__launch_bounds__(512)
__global__ void attn_kernel(const u16* __restrict__ Q, const u16* __restrict__ K,
                            const u16* __restrict__ Vt, u16* __restrict__ O,
                            const int* __restrict__ is_causal_p) {
    __shared__ __align__(16) u16 Ks[64][136];
    __shared__ __align__(16) u16 Vts[128][72];
    __shared__ __align__(16) u16 Pb[8][16][72];

    const int tid  = threadIdx.x;
    const int lane = tid & 63;
    const int w    = tid >> 6;                 // 0..7
    const int qm   = lane & 15;
    const int quad = lane >> 4;
    const int xt   = ((blockIdx.y >> 3) & 1) ? (gridDim.x - 1 - blockIdx.x)
                                             : blockIdx.x;
    const int q0   = xt * 128;
    const int h    = blockIdx.y;
    const int causal = *is_causal_p;
    const float scale = 0.08838834764831845f;  // 1/sqrt(128)
    const float SHIFT = 16.0f;                 // exact (softmax shift-invariant)

    short8 qf[4];
    {
        const u16* qptr = Q + (size_t)(q0 + w * 16 + qm) * DM + h * HD;
#pragma unroll
        for (int kc = 0; kc < 4; kc++)
            qf[kc] = *(const short8*)&qptr[kc * 32 + quad * 8];
    }

    floatx4 o[8];
#pragma unroll
    for (int dt = 0; dt < 8; dt++) o[dt] = floatx4{0.f, 0.f, 0.f, 0.f};
    float l_part[4] = {0.f, 0.f, 0.f, 0.f};

    const int jend = causal ? (q0 + 128) : SEQ;

    // staging map (512 thr): chunk c = tid + p*512
    const int kr0 = tid >> 4;            // K row (p adds 32)
    const int kc8 = (tid & 15) * 8;
    const int vd0 = tid >> 3;            // V d   (p adds 64)
    const int vc8 = (tid & 7) * 8;

    short8 kreg[2], vreg[2];
#pragma unroll
    for (int p = 0; p < 2; p++) {
        kreg[p] = *(const short8*)&K[(size_t)(kr0 + p * 32) * DM + h * HD + kc8];
        vreg[p] = *(const short8*)&Vt[(size_t)(h * HD + vd0 + p * 64) * SEQ + vc8];
    }

    for (int j0 = 0; j0 < jend; j0 += 64) {
        // commit prefetched tile to LDS
#pragma unroll
        for (int p = 0; p < 2; p++) {
            *(short8*)&Ks[kr0 + p * 32][kc8] = kreg[p];
            *(short8*)&Vts[vd0 + p * 64][vc8] = vreg[p];
        }
        __syncthreads();

        // prefetch next tile into regs (latency hidden behind compute)
        const int jn = (j0 + 64 < jend) ? j0 + 64 : 0;
#pragma unroll
        for (int p = 0; p < 2; p++) {
            kreg[p] = *(const short8*)&K[(size_t)(jn + kr0 + p * 32) * DM + h * HD + kc8];
            vreg[p] = *(const short8*)&Vt[(size_t)(h * HD + vd0 + p * 64) * SEQ + jn + vc8];
        }

        // S = Q @ K^T
        floatx4 s[4];
#pragma unroll
        for (int nt = 0; nt < 4; nt++) s[nt] = floatx4{0.f, 0.f, 0.f, 0.f};
#pragma unroll
        for (int kc = 0; kc < 4; kc++)
#pragma unroll
            for (int nt = 0; nt < 4; nt++) {
                short8 b = *(const short8*)&Ks[nt * 16 + qm][kc * 32 + quad * 8];
                s[nt] = __builtin_amdgcn_mfma_f32_16x16x32_bf16(qf[kc], b, s[nt], 0, 0, 0);
            }

        // P = exp(S*scale - SHIFT), masked; per-lane partial row sums
        const bool mask = causal && (j0 + 64 > q0 + w * 16);
#pragma unroll
        for (int r = 0; r < 4; r++) {
            const int qg = q0 + w * 16 + quad * 4 + r;
#pragma unroll
            for (int nt = 0; nt < 4; nt++) {
                float v = fmaf(s[nt][r], scale, -SHIFT);
                if (mask && (j0 + nt * 16 + qm > qg)) v = -1e30f;
                const float p = __expf(v);
                l_part[r] += p;
                Pb[w][quad * 4 + r][nt * 16 + qm] = f2b(p);
            }
        }
        asm volatile("s_waitcnt lgkmcnt(0)" ::: "memory");  // Pb is wave-local

        // O += P @ V
#pragma unroll
        for (int kc = 0; kc < 2; kc++) {
            short8 pf = *(const short8*)&Pb[w][qm][kc * 32 + quad * 8];
#pragma unroll
            for (int dt = 0; dt < 8; dt++) {
                short8 b = *(const short8*)&Vts[dt * 16 + qm][kc * 32 + quad * 8];
                o[dt] = __builtin_amdgcn_mfma_f32_16x16x32_bf16(pf, b, o[dt], 0, 0, 0);
            }
        }
        __syncthreads();   // all waves done reading Ks/Vts before next commit
    }

    // Epilogue: quad-local l reduction, normalize, store
#pragma unroll
    for (int r = 0; r < 4; r++) {
        float l = l_part[r];
#pragma unroll
        for (int off = 8; off >= 1; off >>= 1)
            l += __shfl_xor(l, off, 64);
        const float inv = 1.0f / l;
        const int qg = q0 + w * 16 + quad * 4 + r;
#pragma unroll
        for (int dt = 0; dt < 8; dt++) {
            const int d = h * HD + dt * 16 + qm;
            O[(size_t)qg * DM + d] = f2b(o[dt][r] * inv);
        }
    }
}

// ---------------------------------------------------------------------------
extern "C" void kernel_launch(void* const* d_in, const int* in_sizes, int n_in,
                              void* d_out, int out_size, void* d_ws, size_t ws_size,
                              hipStream_t stream) {
    const int* isc = (const int*)d_in[9];

    int* flag = (int*)d_ws;
    u16* base = (u16*)((char*)d_ws + 256);

    const int NX = SEQ * DM;       // 8388608
    const int NW = DM * DM;        // 4194304
    const int NB = DM;

    // ws layout (u16 elems from base):
    unsigned long long off = 0;
    const unsigned long long oXc   = off; off += NX;
    const unsigned long long oWall = off; off += 3ull * NW;  // Wq,Wk,Wv
    const unsigned long long oWo   = off; off += NW;
    const unsigned long long oBall = off; off += 3ull * NB;  // bq,bk,bv
    const unsigned long long oBo   = off; off += NB;
    const unsigned long long oQ    = off; off += NX;
    const unsigned long long oK    = off; off += NX;
    const unsigned long long oVt   = off; off += NX;
    const unsigned long long oA    = off; off += NX;

    detect_dtype<<<1, 256, 0, stream>>>((const u16*)d_in[0], flag);

    ConvArgs ca;
    const unsigned long long dsts[9] = {oXc, oWall, oBall, oWall + NW, oBall + NB,
                                        oWall + 2ull * NW, oBall + 2ull * NB, oWo, oBo};
    for (int i = 0; i < 9; i++) {
        ca.src[i] = d_in[i];
        ca.dstoff[i] = dsts[i];
        ca.n[i] = in_sizes[i];
    }
    convert_all<<<dim3(NX / 8 / 256, 9), 256, 0, stream>>>(ca, base, flag);

    gemm_qkv<<<dim3(3 * DM / 256, SEQ / 256), 512, 0, stream>>>(
        base + oXc, base + oWall, base + oBall,
        base + oQ, base + oK, base + oVt);

    attn_kernel<<<dim3(SEQ / 128, NH), 512, 0, stream>>>(
        base + oQ, base + oK, base + oVt, base + oA, isc);

    gemm_out<<<dim3(DM / 256, SEQ / 256), 512, 0, stream>>>(
        base + oA, base + oWo, base + oBo, d_out, flag);
}

// Round 3
// 462.511 us; speedup vs baseline: 1.0864x; 1.0371x over previous
//
#include <hip/hip_runtime.h>
#include <hip/hip_bf16.h>

typedef unsigned short u16;
typedef __attribute__((ext_vector_type(8))) short short8;
typedef __attribute__((ext_vector_type(4))) short short4v;
typedef __attribute__((ext_vector_type(4))) float floatx4;

constexpr int SEQ = 4096;
constexpr int DM  = 2048;
constexpr int NH  = 16;
constexpr int HD  = 128;

__device__ inline u16 f2b(float f) {
    __hip_bfloat16 h = __float2bfloat16(f);
    return *reinterpret_cast<u16*>(&h);
}
__device__ inline float b2f(u16 u) {
    __hip_bfloat16 h = *reinterpret_cast<__hip_bfloat16*>(&u);
    return __bfloat162float(h);
}

__device__ __forceinline__ void async_copy16(const u16* g, u16* lds_base) {
    __builtin_amdgcn_global_load_lds(
        (const __attribute__((address_space(1))) unsigned int*)g,
        (__attribute__((address_space(3))) unsigned int*)lds_base,
        16, 0, 0);
}

// ---------------------------------------------------------------------------
__global__ void detect_dtype(const u16* __restrict__ X, int* __restrict__ flag) {
    __shared__ int cnt;
    if (threadIdx.x == 0) cnt = 0;
    __syncthreads();
    int local = 0;
    for (int i = threadIdx.x; i < 4096; i += 256) {
        int e = (X[i] >> 7) & 0xFF;
        if (e >= 0x3C && e <= 0x8D) local++;
    }
    atomicAdd(&cnt, local);
    __syncthreads();
    if (threadIdx.x == 0) *flag = (cnt >= 3890) ? 1 : 0;
}

// One launch converts all 9 float tensors (bf16 passthrough or fp32 round).
struct ConvArgs {
    const void* src[9];
    unsigned long long dstoff[9];  // u16-element offset from base
    int n[9];
};
__global__ void convert_all(ConvArgs a, u16* __restrict__ base,
                            const int* __restrict__ flag) {
    const int t = blockIdx.y;
    const int n = a.n[t];
    const int i = (blockIdx.x * blockDim.x + threadIdx.x) * 8;
    if (i >= n) return;
    u16* out = base + a.dstoff[t];
    if (*flag) {
        *(short8*)&out[i] = *(const short8*)&((const u16*)a.src[t])[i];
    } else {
        const float* p = (const float*)a.src[t];
        u16 tmp[8];
#pragma unroll
        for (int j = 0; j < 8; j++) tmp[j] = f2b(p[i + j]);
        *(short8*)&out[i] = *(const short8*)tmp;
    }
}

// ---------------------------------------------------------------------------
// 256x128 GEMM core, 2-sync-per-K-tile counted-vmcnt schedule.
//   BM=256, BN=128, BK=64, 512 threads = 8 waves (4M x 2N), wave out 64x64,
//   acc[4][4] = 64 regs/lane (half of 256^2 -> scheduler headroom).
//   LDS: 2 parity slots x (A 32KB + B 16KB) = 96 KiB -> 1 block/CU.
//   Grid geometry: qkv 48x16=768 = 3 full rounds; out 16x16=256 = 1 round
//   (kills the 25%/50% tail-round waste of the 256^2 version).
//   T2 swizzle: linear global_load_lds dest, inverse-swizzled global SOURCE,
//      swizzled ds_read (granule ^= row&7). Bank conflicts measured 0.
//   Ledger (per wave, issue order):  S1(t): B(t+2) x2;  S2(t): A(t+2) x4.
//   At S2(t) pre-wait outstanding = {A(t+1)4, B(t+2)2}; vmcnt(2) forces
//   tile t+1 fully landed, leaves B(t+2) in flight. Prologue: 12 loads,
//   vmcnt(6) = tile0 landed, tile1 in flight.
// ---------------------------------------------------------------------------
__device__ __forceinline__ void gemm256x128_core(
    const u16* __restrict__ A, const u16* __restrict__ W,
    int m0, int n0, floatx4 (&acc)[4][4])
{
    __shared__ __align__(16) u16 As[2][16384];   // 256 x 64
    __shared__ __align__(16) u16 Bs[2][8192];    // 128 x 64
    constexpr int K  = DM;
    constexpr int NT = K / 64;   // 32

    const int tid  = threadIdx.x;
    const int lane = tid & 63;
    const int w    = tid >> 6;            // 0..7
    const int qm   = lane & 15;
    const int quad = lane >> 4;
    const int wm   = (w >> 1) * 64;       // wave row offset: 0/64/128/192
    const int wn   = (w & 1) * 64;        // wave col offset: 0/64

    // staging map: thread t covers LDS linear bytes [slot*8192 + t*16, +16)
    // source pre-swizzle: global granule = (t&7) ^ (row&7).
    const int srow = tid >> 3;                       // 0..63
    const int scol = ((tid & 7) ^ (srow & 7)) * 8;   // elems

    // frag-read swizzle: physical granule = (kh*4+quad) ^ (row&7); row&7==qm&7
    const int fo0 = (quad ^ (qm & 7)) * 8;   // kh=0 elem offset within row
    const int fo1 = fo0 ^ 32;                // kh=1

    const u16* Ag = A + (size_t)(m0 + srow) * K + scol;
    const u16* Wg = W + (size_t)(n0 + srow) * K + scol;

#define STG_A4(par, k0) {                                                 \
    async_copy16(Ag + (size_t)0 * 64 * K + (k0), &As[par][0 * 4096 + w * 512]); \
    async_copy16(Ag + (size_t)1 * 64 * K + (k0), &As[par][1 * 4096 + w * 512]); \
    async_copy16(Ag + (size_t)2 * 64 * K + (k0), &As[par][2 * 4096 + w * 512]); \
    async_copy16(Ag + (size_t)3 * 64 * K + (k0), &As[par][3 * 4096 + w * 512]); }
#define STG_B2(par, k0) {                                                 \
    async_copy16(Wg + (size_t)0 * 64 * K + (k0), &Bs[par][0 * 4096 + w * 512]); \
    async_copy16(Wg + (size_t)1 * 64 * K + (k0), &Bs[par][1 * 4096 + w * 512]); }

#define RD_A(d0, d1, row) { d0 = *(const short8*)&Ac[(row) * 64 + fo0];   \
                            d1 = *(const short8*)&Ac[(row) * 64 + fo1]; }

#define MFMA_G(g, x0, x1) {                                               \
    __builtin_amdgcn_s_setprio(1);                                        \
    _Pragma("unroll")                                                     \
    for (int nt = 0; nt < 4; ++nt) {                                      \
        acc[g][nt] = __builtin_amdgcn_mfma_f32_16x16x32_bf16(x0, rB[nt][0], acc[g][nt], 0, 0, 0); \
        acc[g][nt] = __builtin_amdgcn_mfma_f32_16x16x32_bf16(x1, rB[nt][1], acc[g][nt], 0, 0, 0); \
    }                                                                     \
    __builtin_amdgcn_s_setprio(0); }

#pragma unroll
    for (int i = 0; i < 4; ++i)
#pragma unroll
        for (int j = 0; j < 4; ++j) acc[i][j] = floatx4{0.f, 0.f, 0.f, 0.f};

    // Prologue: tiles 0 and 1 (12 loads); wait tile 0 (allow tile 1's 6).
    STG_A4(0, 0);
    STG_B2(0, 0);
    STG_A4(1, 64);
    STG_B2(1, 64);
    asm volatile("s_waitcnt vmcnt(6)" ::: "memory");
    __builtin_amdgcn_s_barrier();
    asm volatile("" ::: "memory");

    for (int t = 0; t < NT; ++t) {
        const int p = t & 1;
        const u16* Ac = As[p];
        const u16* Bc = Bs[p];
        const bool more = (t + 2 < NT);
        const int kf = (t + 2) * 64;

        short8 rB[4][2];
        short8 a0, a1, a2, a3, b0, b1, c0, c1;

        // ---- phase 1: B frags + A groups 0,1; MFMA g0
#pragma unroll
        for (int nt = 0; nt < 4; ++nt) {
            const int br = wn + nt * 16 + qm;
            rB[nt][0] = *(const short8*)&Bc[br * 64 + fo0];
            rB[nt][1] = *(const short8*)&Bc[br * 64 + fo1];
        }
        RD_A(a0, a1, wm + qm);
        RD_A(a2, a3, wm + 16 + qm);
        MFMA_G(0, a0, a1);

        // ---- phase 2: read A group 2; MFMA g1
        RD_A(b0, b1, wm + 32 + qm);
        MFMA_G(1, a2, a3);

        // ---- S1: B(t) reads done by all waves -> stage B(t+2) into Bs[p]
        asm volatile("" ::: "memory");
        __builtin_amdgcn_s_barrier();
        asm volatile("" ::: "memory");
        if (more) { STG_B2(p, kf); }

        // ---- phase 3: read A group 3; MFMA g2
        RD_A(c0, c1, wm + 48 + qm);
        MFMA_G(2, b0, b1);

        // ---- phase 4: MFMA g3
        MFMA_G(3, c0, c1);

        // ---- S2: counted wait (tile t+1 landed; B(t+2)'s 2 may fly);
        //          A(t) reads done -> stage A(t+2) into As[p]
        if (more) asm volatile("s_waitcnt vmcnt(2)" ::: "memory");
        else      asm volatile("s_waitcnt vmcnt(0)" ::: "memory");
        __builtin_amdgcn_s_barrier();
        asm volatile("" ::: "memory");
        if (more) { STG_A4(p, kf); }
    }
#undef STG_A4
#undef STG_B2
#undef RD_A
#undef MFMA_G
}

// ---------------------------------------------------------------------------
// Fused QKV GEMM: [Q|K|V](4096x6144) = X @ Wall^T + ball. Q,K row-major;
// V written transposed. 256x128 tiles -> grid (48,16) = 768 = 3 full rounds.
// ---------------------------------------------------------------------------
__launch_bounds__(512, 2)
__global__ void gemm_qkv(const u16* __restrict__ A, const u16* __restrict__ W,
                         const u16* __restrict__ bias,
                         u16* __restrict__ Qb, u16* __restrict__ Kb,
                         u16* __restrict__ VtG) {
    const int m0 = blockIdx.y * 256;
    const int n0 = blockIdx.x * 128;
    floatx4 acc[4][4];
    gemm256x128_core(A, W, m0, n0, acc);

    const int tid  = threadIdx.x;
    const int lane = tid & 63;
    const int w    = tid >> 6;
    const int qm   = lane & 15;
    const int quad = lane >> 4;
    const int wm   = (w >> 1) * 64;
    const int wn   = (w & 1) * 64;

    const int buf = n0 >> 11;  // 0=Q, 1=K, 2=V (block-uniform: 2048%128==0)
    if (buf < 2) {
        u16* Y = (buf == 0) ? Qb : Kb;
#pragma unroll
        for (int nt = 0; nt < 4; ++nt) {
            const int gcol = n0 + wn + nt * 16 + qm;
            const int col  = gcol & 2047;
            const float bv = b2f(bias[gcol]);
#pragma unroll
            for (int mt = 0; mt < 4; ++mt) {
                const int rbase = m0 + wm + mt * 16 + quad * 4;
#pragma unroll
                for (int r = 0; r < 4; ++r)
                    Y[(size_t)(rbase + r) * DM + col] = f2b(acc[mt][nt][r] + bv);
            }
        }
    } else {
#pragma unroll
        for (int nt = 0; nt < 4; ++nt) {
            const int gcol = n0 + wn + nt * 16 + qm;
            const int col  = gcol & 2047;            // d-index
            const float bv = b2f(bias[gcol]);
#pragma unroll
            for (int mt = 0; mt < 4; ++mt) {
                const int rbase = m0 + wm + mt * 16 + quad * 4;
                u16 tmp[4];
#pragma unroll
                for (int r = 0; r < 4; ++r)
                    tmp[r] = f2b(acc[mt][nt][r] + bv);
                *(short4v*)&VtG[(size_t)col * SEQ + rbase] = *(const short4v*)tmp;
            }
        }
    }
}

// ---------------------------------------------------------------------------
// Output GEMM: d_out = Ab @ Wo^T + bo, written in the harness's dtype.
// 256x128 tiles -> grid (16,16) = 256 blocks = exactly 1 full round.
// ---------------------------------------------------------------------------
__launch_bounds__(512, 2)
__global__ void gemm_out(const u16* __restrict__ A, const u16* __restrict__ W,
                         const u16* __restrict__ bias, void* __restrict__ out,
                         const int* __restrict__ flag) {
    const int m0 = blockIdx.y * 256;
    const int n0 = blockIdx.x * 128;
    floatx4 acc[4][4];
    gemm256x128_core(A, W, m0, n0, acc);

    const int tid  = threadIdx.x;
    const int lane = tid & 63;
    const int w    = tid >> 6;
    const int qm   = lane & 15;
    const int quad = lane >> 4;
    const int wm   = (w >> 1) * 64;
    const int wn   = (w & 1) * 64;
    const int N    = DM;

    const int f = *flag;
#pragma unroll
    for (int nt = 0; nt < 4; ++nt) {
        const int col = n0 + wn + nt * 16 + qm;
        const float bv = b2f(bias[col]);
#pragma unroll
        for (int mt = 0; mt < 4; ++mt) {
            const int rbase = m0 + wm + mt * 16 + quad * 4;
#pragma unroll
            for (int r = 0; r < 4; ++r) {
                const float v = acc[mt][nt][r] + bv;
                if (f) ((u16*)out)[(size_t)(rbase + r) * N + col] = f2b(v);
                else   ((float*)out)[(size_t)(rbase + r) * N + col] = v;
            }
        }
    }
}

// ---------------------------------------------------------------------------
// Flash attention: unchanged this round (512 thr, 8 waves x 16 q-rows,
// causal balance flip, BK=64, fixed-shift softmax, register-prefetch dbuf).
// ---------------------------------------------------------------------------
__launch_bounds__(512)
__global__ void attn_kernel(const u16* __restrict__ Q, const u16* __restrict__ K,
                            const u16* __restrict__ Vt, u16* __restrict__ O,
                            const int* __restrict__ is_causal_p) {
    __shared__ __align__(16) u16 Ks[64][136];
    __shared__ __align__(16) u16 Vts[128][72];
    __shared__ __align__(16) u16 Pb[8][16][72];

    const int tid  = threadIdx.x;
    const int lane = tid & 63;
    const int w    = tid >> 6;                 // 0..7
    const int qm   = lane & 15;
    const int quad = lane >> 4;
    const int xt   = ((blockIdx.y >> 3) & 1) ? (gridDim.x - 1 - blockIdx.x)
                                             : blockIdx.x;
    const int q0   = xt * 128;
    const int h    = blockIdx.y;
    const int causal = *is_causal_p;
    const float scale = 0.08838834764831845f;  // 1/sqrt(128)
    const float SHIFT = 16.0f;                 // exact (softmax shift-invariant)

    short8 qf[4];
    {
        const u16* qptr = Q + (size_t)(q0 + w * 16 + qm) * DM + h * HD;
#pragma unroll
        for (int kc = 0; kc < 4; kc++)
            qf[kc] = *(const short8*)&qptr[kc * 32 + quad * 8];
    }

    floatx4 o[8];
#pragma unroll
    for (int dt = 0; dt < 8; dt++) o[dt] = floatx4{0.f, 0.f, 0.f, 0.f};
    float l_part[4] = {0.f, 0.f, 0.f, 0.f};

    const int jend = causal ? (q0 + 128) : SEQ;

    // staging map (512 thr): chunk c = tid + p*512
    const int kr0 = tid >> 4;            // K row (p adds 32)
    const int kc8 = (tid & 15) * 8;
    const int vd0 = tid >> 3;            // V d   (p adds 64)
    const int vc8 = (tid & 7) * 8;

    short8 kreg[2], vreg[2];
#pragma unroll
    for (int p = 0; p < 2; p++) {
        kreg[p] = *(const short8*)&K[(size_t)(kr0 + p * 32) * DM + h * HD + kc8];
        vreg[p] = *(const short8*)&Vt[(size_t)(h * HD + vd0 + p * 64) * SEQ + vc8];
    }

    for (int j0 = 0; j0 < jend; j0 += 64) {
        // commit prefetched tile to LDS
#pragma unroll
        for (int p = 0; p < 2; p++) {
            *(short8*)&Ks[kr0 + p * 32][kc8] = kreg[p];
            *(short8*)&Vts[vd0 + p * 64][vc8] = vreg[p];
        }
        __syncthreads();

        // prefetch next tile into regs (latency hidden behind compute)
        const int jn = (j0 + 64 < jend) ? j0 + 64 : 0;
#pragma unroll
        for (int p = 0; p < 2; p++) {
            kreg[p] = *(const short8*)&K[(size_t)(jn + kr0 + p * 32) * DM + h * HD + kc8];
            vreg[p] = *(const short8*)&Vt[(size_t)(h * HD + vd0 + p * 64) * SEQ + jn + vc8];
        }

        // S = Q @ K^T
        floatx4 s[4];
#pragma unroll
        for (int nt = 0; nt < 4; nt++) s[nt] = floatx4{0.f, 0.f, 0.f, 0.f};
#pragma unroll
        for (int kc = 0; kc < 4; kc++)
#pragma unroll
            for (int nt = 0; nt < 4; nt++) {
                short8 b = *(const short8*)&Ks[nt * 16 + qm][kc * 32 + quad * 8];
                s[nt] = __builtin_amdgcn_mfma_f32_16x16x32_bf16(qf[kc], b, s[nt], 0, 0, 0);
            }

        // P = exp(S*scale - SHIFT), masked; per-lane partial row sums
        const bool mask = causal && (j0 + 64 > q0 + w * 16);
#pragma unroll
        for (int r = 0; r < 4; r++) {
            const int qg = q0 + w * 16 + quad * 4 + r;
#pragma unroll
            for (int nt = 0; nt < 4; nt++) {
                float v = fmaf(s[nt][r], scale, -SHIFT);
                if (mask && (j0 + nt * 16 + qm > qg)) v = -1e30f;
                const float p = __expf(v);
                l_part[r] += p;
                Pb[w][quad * 4 + r][nt * 16 + qm] = f2b(p);
            }
        }
        asm volatile("s_waitcnt lgkmcnt(0)" ::: "memory");  // Pb is wave-local

        // O += P @ V
#pragma unroll
        for (int kc = 0; kc < 2; kc++) {
            short8 pf = *(const short8*)&Pb[w][qm][kc * 32 + quad * 8];
#pragma unroll
            for (int dt = 0; dt < 8; dt++) {
                short8 b = *(const short8*)&Vts[dt * 16 + qm][kc * 32 + quad * 8];
                o[dt] = __builtin_amdgcn_mfma_f32_16x16x32_bf16(pf, b, o[dt], 0, 0, 0);
            }
        }
        __syncthreads();   // all waves done reading Ks/Vts before next commit
    }

    // Epilogue: quad-local l reduction, normalize, store
#pragma unroll
    for (int r = 0; r < 4; r++) {
        float l = l_part[r];
#pragma unroll
        for (int off = 8; off >= 1; off >>= 1)
            l += __shfl_xor(l, off, 64);
        const float inv = 1.0f / l;
        const int qg = q0 + w * 16 + quad * 4 + r;
#pragma unroll
        for (int dt = 0; dt < 8; dt++) {
            const int d = h * HD + dt * 16 + qm;
            O[(size_t)qg * DM + d] = f2b(o[dt][r] * inv);
        }
    }
}

// ---------------------------------------------------------------------------
extern "C" void kernel_launch(void* const* d_in, const int* in_sizes, int n_in,
                              void* d_out, int out_size, void* d_ws, size_t ws_size,
                              hipStream_t stream) {
    const int* isc = (const int*)d_in[9];

    int* flag = (int*)d_ws;
    u16* base = (u16*)((char*)d_ws + 256);

    const int NX = SEQ * DM;       // 8388608
    const int NW = DM * DM;        // 4194304
    const int NB = DM;

    // ws layout (u16 elems from base):
    unsigned long long off = 0;
    const unsigned long long oXc   = off; off += NX;
    const unsigned long long oWall = off; off += 3ull * NW;  // Wq,Wk,Wv
    const unsigned long long oWo   = off; off += NW;
    const unsigned long long oBall = off; off += 3ull * NB;  // bq,bk,bv
    const unsigned long long oBo   = off; off += NB;
    const unsigned long long oQ    = off; off += NX;
    const unsigned long long oK    = off; off += NX;
    const unsigned long long oVt   = off; off += NX;
    const unsigned long long oA    = off; off += NX;

    detect_dtype<<<1, 256, 0, stream>>>((const u16*)d_in[0], flag);

    ConvArgs ca;
    const unsigned long long dsts[9] = {oXc, oWall, oBall, oWall + NW, oBall + NB,
                                        oWall + 2ull * NW, oBall + 2ull * NB, oWo, oBo};
    for (int i = 0; i < 9; i++) {
        ca.src[i] = d_in[i];
        ca.dstoff[i] = dsts[i];
        ca.n[i] = in_sizes[i];
    }
    convert_all<<<dim3(NX / 8 / 256, 9), 256, 0, stream>>>(ca, base, flag);

    gemm_qkv<<<dim3(3 * DM / 128, SEQ / 256), 512, 0, stream>>>(
        base + oXc, base + oWall, base + oBall,
        base + oQ, base + oK, base + oVt);

    attn_kernel<<<dim3(SEQ / 128, NH), 512, 0, stream>>>(
        base + oQ, base + oK, base + oVt, base + oA, isc);

    gemm_out<<<dim3(DM / 128, SEQ / 256), 512, 0, stream>>>(
        base + oA, base + oWo, base + oBo, d_out, flag);
}